// Round 5
// baseline (264.417 us; speedup 1.0000x reference)
//
#include <hip/hip_runtime.h>
#include <math.h>

#define D_MODEL 1024
#define D_FF    4096
#define RANK    128
#define M_ROWS  8192

typedef _Float16 f16;
typedef _Float16 f16x8 __attribute__((ext_vector_type(8)));
typedef float    f32x4 __attribute__((ext_vector_type(4)));

#define MFMA16(a, b, c) __builtin_amdgcn_mfma_f32_16x16x32_f16((a), (b), (c), 0, 0, 0)

__device__ __forceinline__ f16x8 ld8(const f16* p) { return *(const f16x8*)p; }

__device__ __forceinline__ f16x8 cvt8(float4 a0, float4 a1) {
    f16x8 r = { (f16)a0.x, (f16)a0.y, (f16)a0.z, (f16)a0.w,
                (f16)a1.x, (f16)a1.y, (f16)a1.z, (f16)a1.w };
    return r;
}

// Fast exact-gelu: erf via Abramowitz-Stegun 7.1.26 (|err| <= 1.5e-7 abs),
// proven R2/R4 (absmax unchanged at 9.77e-4).
__device__ __forceinline__ float gelu_fast(float v) {
    float u  = v * 0.70710678118654752440f;
    float au = fabsf(u);
    float t  = __builtin_amdgcn_rcpf(__builtin_fmaf(0.3275911f, au, 1.0f));
    float e  = __expf(-au * au);
    float p  = __builtin_fmaf(1.061405429f, t, -1.453152027f);
    p = __builtin_fmaf(p, t, 1.421413741f);
    p = __builtin_fmaf(p, t, -0.284496736f);
    p = __builtin_fmaf(p, t, 0.254829592f);
    float er = __builtin_fmaf(-p * t, e, 1.0f);
    er = copysignf(er, u);
    return 0.5f * v * (1.0f + er);
}

// ---------------------------------------------------------------------------
// Prep (verbatim-proven).
// ---------------------------------------------------------------------------
__global__ __launch_bounds__(256) void k_prep(
    const float* __restrict__ cfcU, const float* __restrict__ cfcS,
    const float* __restrict__ cfcV, const float* __restrict__ pjU,
    const float* __restrict__ pjS,  const float* __restrict__ pjV,
    f16* __restrict__ w1T, f16* __restrict__ v1,
    f16* __restrict__ w2T, f16* __restrict__ v2)
{
    int i = blockIdx.x * 256 + threadIdx.x;
    if (i < 131072) {
        int r = i >> 10, d = i & 1023;
        w1T[i] = (f16)(cfcU[d * RANK + r] * cfcS[r]);
    } else if (i < 655360) {
        int j = i - 131072;
        v1[j] = (f16)cfcV[j];
    } else if (i < 1179648) {
        int j = i - 655360;
        int r = j >> 12, f = j & 4095;
        w2T[j] = (f16)(pjU[f * RANK + r] * pjS[r]);
    } else if (i < 1310720) {
        int j = i - 1179648;
        v2[j] = (f16)pjV[j];
    }
}

// ---------------------------------------------------------------------------
// Stage 1 (proven R1): t1p[h][m][r] = x[m][K-half h] @ w1T^T.
// ---------------------------------------------------------------------------
__global__ __launch_bounds__(512, 2) void k_t1(
    const float* __restrict__ x, const f16* __restrict__ w1T,
    f16* __restrict__ t1p)
{
    __shared__ __align__(16) f16 w1s[128 * 520];   // 133120 B

    const int tid  = threadIdx.x;
    const int lane = tid & 63;
    const int wv   = tid >> 6;
    const int wm   = wv & 3, wn = wv >> 2;
    const int m0b  = blockIdx.x * 64;
    const int h    = blockIdx.y;
    const int c    = lane & 15, q = lane >> 4;

#define LOADX(dst, kc)                                                          \
    _Pragma("unroll") for (int kb = 0; kb < 4; ++kb) {                          \
        const float* px = &x[(size_t)(m0b + wm * 16 + c) * D_MODEL +            \
                             h * 512 + (kc) * 128 + kb * 32 + q * 8];           \
        dst[kb][0] = *(const float4*)px;                                        \
        dst[kb][1] = *(const float4*)(px + 4); }

#define COMPUTEKC(src, kc)                                                      \
    _Pragma("unroll") for (int kb = 0; kb < 4; ++kb) {                          \
        f16x8 af = cvt8(src[kb][0], src[kb][1]);                                \
        _Pragma("unroll") for (int nt = 0; nt < 4; ++nt) {                      \
            f16x8 bf = *(const f16x8*)                                          \
                &w1s[(wn * 64 + nt * 16 + c) * 520 + (kc) * 128 + kb * 32 + q * 8]; \
            acc[nt] = MFMA16(af, bf, acc[nt]); } }

    float4 xa[4][2], xb[4][2];
    LOADX(xa, 0)

#pragma unroll
    for (int i = 0; i < 16; ++i) {
        int id = i * 512 + tid;
        int rr = id >> 6, k8 = id & 63;
        *(f16x8*)&w1s[rr * 520 + k8 * 8] =
            ld8(w1T + (size_t)rr * D_MODEL + h * 512 + k8 * 8);
    }
    __syncthreads();

    f32x4 acc[4] = {};
    LOADX(xb, 1)
    COMPUTEKC(xa, 0)
    LOADX(xa, 2)
    COMPUTEKC(xb, 1)
    LOADX(xb, 3)
    COMPUTEKC(xa, 2)
    COMPUTEKC(xb, 3)

    f16* o = t1p + (size_t)h * (M_ROWS * RANK);
#pragma unroll
    for (int nt = 0; nt < 4; ++nt)
#pragma unroll
        for (int i2 = 0; i2 < 4; ++i2)
            o[(size_t)(m0b + wm * 16 + q * 4 + i2) * RANK + wn * 64 + nt * 16 + c] =
                (f16)acc[nt][i2];
#undef LOADX
#undef COMPUTEKC
}

// ---------------------------------------------------------------------------
// Fused stages 2+3 v5: barrier-free loop (R4-proven: 0 bank conflicts, 0
// spill at VGPR=128), now OCCUPANCY-DOUBLED. R4 post-mortem: 2 waves/SIMD
// left ~70% of cycles stalled on L2 latency; VGPR=128 means HW supports 4
// waves/SIMD — we just didn't launch enough blocks. v5: BM=16 (drop the wm2
// dim -> strictly lower reg pressure than what already fit in 128), grid =
// 512 m-tiles x 2 f-halves = 1024 blocks = 4 blocks/CU = 4 waves/SIMD.
// Weight traffic invariant (512 tiles x 1 MB f-half = same 512 MB from L2).
// LDS 16.9 KB/block (68 KB/CU). Everything else byte-identical to R4.
// ---------------------------------------------------------------------------
__global__ __launch_bounds__(256, 4) void k_fused(
    const f16* __restrict__ t1p, const f16* __restrict__ v1,
    const float* __restrict__ bfc, const f16* __restrict__ w2T,
    f16* __restrict__ t2p)
{
    __shared__ __align__(16) char smem[16896];     // hs 8KB | reduce overlay

    const int tid  = threadIdx.x;
    const int lane = tid & 63;
    const int wv   = tid >> 6;                     // 0..3
    const int c    = lane & 15, q = lane >> 4;

    // XCD swizzle (bijective, 1024 = 128*8): XCDs 0-3 -> s=0, 4-7 -> s=1
    const int bx  = blockIdx.x;
    const int s   = (bx & 7) >> 2;
    const int mb  = (bx >> 3) * 4 + (bx & 3);      // 0..511
    const int m0b = mb * 16;
    const int f00 = s * 2048 + wv * 512;

    char* hsb = &smem[wv * 2048];                  // per-wave h scratch [16][128B]

    // A2 fragments: f16 sum of the two t1 partials (proven), 16 rows
    f16x8 a2[4];
#pragma unroll
    for (int kb = 0; kb < 4; ++kb) {
        const size_t off = (size_t)(m0b + c) * RANK + kb * 32 + q * 8;
        f16x8 p0 = ld8(t1p + off);
        f16x8 p1 = ld8(t1p + (size_t)(M_ROWS * RANK) + off);
#pragma unroll
        for (int e = 0; e < 8; ++e)
            a2[kb][e] = (f16)((float)p0[e] + (float)p1[e]);
    }

    f32x4 c3[8] = {};

#pragma unroll 1
    for (int ch = 0; ch < 8; ++ch) {
        const int f0 = f00 + ch * 64;

        // ---- load stage-2 B frags (bv dies at end of stage 2)
        f16x8 bv[4][4];
#pragma unroll
        for (int nt = 0; nt < 4; ++nt)
#pragma unroll
            for (int kb = 0; kb < 4; ++kb)
                bv[nt][kb] = ld8(v1 + (size_t)(f0 + nt * 16 + c) * RANK + kb * 32 + q * 8);
        // bias loads fly under stage 2
        float bb[4];
#pragma unroll
        for (int nt = 0; nt < 4; ++nt)
            bb[nt] = bfc[f0 + nt * 16 + c];

        // ---- stage 2: h-tile = t1 @ v1^T
        f32x4 c2[4] = {};
#pragma unroll
        for (int nt = 0; nt < 4; ++nt)
#pragma unroll
            for (int kb = 0; kb < 4; ++kb)
                c2[nt] = MFMA16(a2[kb], bv[nt][kb], c2[nt]);

        // ---- issue stage-3 B frags now; gelu's VALU hides their latency
        f16x8 bw[2][8];
#pragma unroll
        for (int kb2 = 0; kb2 < 2; ++kb2)
#pragma unroll
            for (int rt = 0; rt < 8; ++rt)
                bw[kb2][rt] = ld8(w2T + (size_t)(rt * 16 + c) * D_FF +
                                  f0 + kb2 * 32 + q * 8);

        // ---- bias + gelu -> per-wave hs, XOR-swizzled rows of 128 B
#pragma unroll
        for (int nt = 0; nt < 4; ++nt)
#pragma unroll
            for (int i2 = 0; i2 < 4; ++i2) {
                int row = q * 4 + i2;
                int col = ((nt * 16 + c) * 2) ^ ((row & 7) << 4);
                *(f16*)(hsb + row * 128 + col) =
                    (f16)gelu_fast(c2[nt][i2] + bb[nt]);
            }
        asm volatile("s_waitcnt lgkmcnt(0)" ::: "memory"); // cross-lane RAW

        // ---- stage 3: c3 += h @ w2T^T
#pragma unroll
        for (int kb2 = 0; kb2 < 2; ++kb2) {
            int row = c;
            int col = (kb2 * 64 + q * 16) ^ ((row & 7) << 4);
            f16x8 a3 = *(const f16x8*)(hsb + row * 128 + col);
#pragma unroll
            for (int rt = 0; rt < 8; ++rt)
                c3[rt] = MFMA16(a3, bw[kb2][rt], c3[rt]);
        }
        asm volatile("s_waitcnt lgkmcnt(0)" ::: "memory"); // WAR on hs
    }

    // ---- epilogue: 4-way tree reduce of c3 over wv, write f16 partial t2p[s]
    float* rbuf = (float*)smem;                    // 2 regions of [16][132] f32

#define ST_C3(w)                                                                \
    { float* rb = rbuf + (w) * 2112;                                            \
      _Pragma("unroll") for (int rt = 0; rt < 8; ++rt)                          \
      _Pragma("unroll") for (int i2 = 0; i2 < 4; ++i2)                          \
          rb[(q * 4 + i2) * 132 + rt * 16 + c] = c3[rt][i2]; }
#define ADD_C3(w)                                                               \
    { float* rb = rbuf + (w) * 2112;                                            \
      _Pragma("unroll") for (int rt = 0; rt < 8; ++rt)                          \
      _Pragma("unroll") for (int i2 = 0; i2 < 4; ++i2)                          \
          c3[rt][i2] += rb[(q * 4 + i2) * 132 + rt * 16 + c]; }

    __syncthreads();                               // all waves done with hs
    if (wv >= 2) ST_C3(wv - 2)
    __syncthreads();
    if (wv < 2) ADD_C3(wv)
    __syncthreads();
    if (wv == 1) ST_C3(0)
    __syncthreads();
    if (wv == 0) {
        ADD_C3(0)
        f16* o = t2p + (size_t)s * (M_ROWS * RANK);
#pragma unroll
        for (int rt = 0; rt < 8; ++rt)
#pragma unroll
            for (int i2 = 0; i2 < 4; ++i2)
                o[(size_t)(m0b + q * 4 + i2) * RANK + rt * 16 + c] =
                    (f16)c3[rt][i2];
    }
#undef ST_C3
#undef ADD_C3
}

// ---------------------------------------------------------------------------
// Stage 4 (proven R0/R1): out = (t2p0+t2p1) @ v2^T + bpj, fp32 out.
// ---------------------------------------------------------------------------
__global__ __launch_bounds__(256, 2) void k_out(
    const f16* __restrict__ t2p, const f16* __restrict__ v2,
    const float* __restrict__ bpj, float* __restrict__ out)
{
    __shared__ __align__(16) f16 v2s[256 * 136];

    const int tid  = threadIdx.x;
    const int lane = tid & 63;
    const int wv   = tid >> 6;
    const int wm   = wv & 1, wn = wv >> 1;
    const int m0b  = blockIdx.x * 32;
    const int n0b  = blockIdx.y * 256;
    const int c    = lane & 15, q = lane >> 4;

#pragma unroll
    for (int i8 = 0; i8 < 16; ++i8) {
        int id = i8 * 256 + tid;
        int nn = id >> 4, k8 = id & 15;
        *(f16x8*)&v2s[nn * 136 + k8 * 8] =
            ld8(v2 + (size_t)(n0b + nn) * RANK + k8 * 8);
    }

    f16x8 a[4];
#pragma unroll
    for (int kb = 0; kb < 4; ++kb) {
        const size_t off = (size_t)(m0b + wm * 16 + c) * RANK + kb * 32 + q * 8;
        f16x8 p0 = ld8(t2p + off);
        f16x8 p1 = ld8(t2p + (size_t)(M_ROWS * RANK) + off);
#pragma unroll
        for (int e = 0; e < 8; ++e)
            a[kb][e] = (f16)((float)p0[e] + (float)p1[e]);
    }
    __syncthreads();

    f32x4 acc[8] = {};
#pragma unroll
    for (int nt = 0; nt < 8; ++nt)
#pragma unroll
        for (int kb = 0; kb < 4; ++kb) {
            f16x8 bf = *(const f16x8*)
                &v2s[(wn * 128 + nt * 16 + c) * 136 + kb * 32 + q * 8];
            acc[nt] = MFMA16(a[kb], bf, acc[nt]);
        }

#pragma unroll
    for (int nt = 0; nt < 8; ++nt) {
        float b = bpj[n0b + wn * 128 + nt * 16 + c];
#pragma unroll
        for (int i2 = 0; i2 < 4; ++i2)
            out[(size_t)(m0b + wm * 16 + q * 4 + i2) * D_MODEL +
                n0b + wn * 128 + nt * 16 + c] = acc[nt][i2] + b;
    }
}

extern "C" void kernel_launch(void* const* d_in, const int* in_sizes, int n_in,
                              void* d_out, int out_size, void* d_ws, size_t ws_size,
                              hipStream_t stream) {
    const float* x    = (const float*)d_in[0];
    const float* cfcU = (const float*)d_in[1];
    const float* cfcS = (const float*)d_in[2];
    const float* cfcV = (const float*)d_in[3];
    const float* cfcB = (const float*)d_in[4];
    const float* pjU  = (const float*)d_in[5];
    const float* pjS  = (const float*)d_in[6];
    const float* pjV  = (const float*)d_in[7];
    const float* pjB  = (const float*)d_in[8];
    float* out = (float*)d_out;

    // ws layout (f16 elements), 10.5 MB (12 MB proven safe):
    f16* wsf = (f16*)d_ws;
    f16* t1p = wsf;                 // [2][8192*128]  4 MB
    f16* t2p = wsf + 2097152;       // [2][8192*128]  4 MB
    f16* w1T = wsf + 4194304;       // [128*1024]
    f16* v1  = w1T + 131072;        // [4096*128]
    f16* w2T = v1  + 524288;        // [128*4096]
    f16* v2  = w2T + 524288;        // [1024*128]

    k_prep <<<dim3(5120), 256, 0, stream>>>(cfcU, cfcS, cfcV, pjU, pjS, pjV,
                                            w1T, v1, w2T, v2);
    k_t1   <<<dim3(M_ROWS / 64, 2), 512, 0, stream>>>(x, w1T, t1p);
    k_fused<<<dim3(1024), 256, 0, stream>>>(t1p, v1, cfcB, w2T, t2p);
    k_out  <<<dim3(M_ROWS / 32, D_MODEL / 256), 256, 0, stream>>>(t2p, v2, pjB, out);
}

// Round 6
// 240.608 us; speedup vs baseline: 1.0990x; 1.0990x over previous
//
#include <hip/hip_runtime.h>
#include <math.h>

#define D_MODEL 1024
#define D_FF    4096
#define RANK    128
#define M_ROWS  8192

typedef _Float16 f16;
typedef _Float16 f16x8 __attribute__((ext_vector_type(8)));
typedef float    f32x4 __attribute__((ext_vector_type(4)));

#define MFMA16(a, b, c) __builtin_amdgcn_mfma_f32_16x16x32_f16((a), (b), (c), 0, 0, 0)

__device__ __forceinline__ f16x8 ld8(const f16* p) { return *(const f16x8*)p; }

__device__ __forceinline__ f16x8 cvt8(float4 a0, float4 a1) {
    f16x8 r = { (f16)a0.x, (f16)a0.y, (f16)a0.z, (f16)a0.w,
                (f16)a1.x, (f16)a1.y, (f16)a1.z, (f16)a1.w };
    return r;
}

// Fast exact-gelu: erf via Abramowitz-Stegun 7.1.26 (|err| <= 1.5e-7 abs),
// proven R2/R4 (absmax unchanged at 9.77e-4).
__device__ __forceinline__ float gelu_fast(float v) {
    float u  = v * 0.70710678118654752440f;
    float au = fabsf(u);
    float t  = __builtin_amdgcn_rcpf(__builtin_fmaf(0.3275911f, au, 1.0f));
    float e  = __expf(-au * au);
    float p  = __builtin_fmaf(1.061405429f, t, -1.453152027f);
    p = __builtin_fmaf(p, t, 1.421413741f);
    p = __builtin_fmaf(p, t, -0.284496736f);
    p = __builtin_fmaf(p, t, 0.254829592f);
    float er = __builtin_fmaf(-p * t, e, 1.0f);
    er = copysignf(er, u);
    return 0.5f * v * (1.0f + er);
}

// ---------------------------------------------------------------------------
// Prep (verbatim-proven).
// ---------------------------------------------------------------------------
__global__ __launch_bounds__(256) void k_prep(
    const float* __restrict__ cfcU, const float* __restrict__ cfcS,
    const float* __restrict__ cfcV, const float* __restrict__ pjU,
    const float* __restrict__ pjS,  const float* __restrict__ pjV,
    f16* __restrict__ w1T, f16* __restrict__ v1,
    f16* __restrict__ w2T, f16* __restrict__ v2)
{
    int i = blockIdx.x * 256 + threadIdx.x;
    if (i < 131072) {
        int r = i >> 10, d = i & 1023;
        w1T[i] = (f16)(cfcU[d * RANK + r] * cfcS[r]);
    } else if (i < 655360) {
        int j = i - 131072;
        v1[j] = (f16)cfcV[j];
    } else if (i < 1179648) {
        int j = i - 655360;
        int r = j >> 12, f = j & 4095;
        w2T[j] = (f16)(pjU[f * RANK + r] * pjS[r]);
    } else if (i < 1310720) {
        int j = i - 1179648;
        v2[j] = (f16)pjV[j];
    }
}

// ---------------------------------------------------------------------------
// Stage 1 (proven R1): t1p[h][m][r] = x[m][K-half h] @ w1T^T.
// ---------------------------------------------------------------------------
__global__ __launch_bounds__(512, 2) void k_t1(
    const float* __restrict__ x, const f16* __restrict__ w1T,
    f16* __restrict__ t1p)
{
    __shared__ __align__(16) f16 w1s[128 * 520];   // 133120 B

    const int tid  = threadIdx.x;
    const int lane = tid & 63;
    const int wv   = tid >> 6;
    const int wm   = wv & 3, wn = wv >> 2;
    const int m0b  = blockIdx.x * 64;
    const int h    = blockIdx.y;
    const int c    = lane & 15, q = lane >> 4;

#define LOADX(dst, kc)                                                          \
    _Pragma("unroll") for (int kb = 0; kb < 4; ++kb) {                          \
        const float* px = &x[(size_t)(m0b + wm * 16 + c) * D_MODEL +            \
                             h * 512 + (kc) * 128 + kb * 32 + q * 8];           \
        dst[kb][0] = *(const float4*)px;                                        \
        dst[kb][1] = *(const float4*)(px + 4); }

#define COMPUTEKC(src, kc)                                                      \
    _Pragma("unroll") for (int kb = 0; kb < 4; ++kb) {                          \
        f16x8 af = cvt8(src[kb][0], src[kb][1]);                                \
        _Pragma("unroll") for (int nt = 0; nt < 4; ++nt) {                      \
            f16x8 bf = *(const f16x8*)                                          \
                &w1s[(wn * 64 + nt * 16 + c) * 520 + (kc) * 128 + kb * 32 + q * 8]; \
            acc[nt] = MFMA16(af, bf, acc[nt]); } }

    float4 xa[4][2], xb[4][2];
    LOADX(xa, 0)

#pragma unroll
    for (int i = 0; i < 16; ++i) {
        int id = i * 512 + tid;
        int rr = id >> 6, k8 = id & 63;
        *(f16x8*)&w1s[rr * 520 + k8 * 8] =
            ld8(w1T + (size_t)rr * D_MODEL + h * 512 + k8 * 8);
    }
    __syncthreads();

    f32x4 acc[4] = {};
    LOADX(xb, 1)
    COMPUTEKC(xa, 0)
    LOADX(xa, 2)
    COMPUTEKC(xb, 1)
    LOADX(xb, 3)
    COMPUTEKC(xa, 2)
    COMPUTEKC(xb, 3)

    f16* o = t1p + (size_t)h * (M_ROWS * RANK);
#pragma unroll
    for (int nt = 0; nt < 4; ++nt)
#pragma unroll
        for (int i2 = 0; i2 < 4; ++i2)
            o[(size_t)(m0b + wm * 16 + q * 4 + i2) * RANK + wn * 64 + nt * 16 + c] =
                (f16)acc[nt][i2];
#undef LOADX
#undef COMPUTEKC
}

// ---------------------------------------------------------------------------
// Fused stages 2+3 v6 = R5 structure + R4 register budget.
// R5 post-mortem: launch_bounds(256,4) made hipcc cap VGPR at 64 -> 89 MB
// spill writes (WRITE_SIZE smoking gun). R4 proved (256,2) -> 128-VGPR cap,
// zero spill. Residency comes from ACTUAL VGPR use (128 -> 4 waves/SIMD),
// not the declared minimum, so (256,2) + grid 1024 + LDS 16.9 KB still
// yields 4 blocks/CU. BM=16, barrier-free loop, B-frags direct from
// L2-resident weights (XCD swizzle: each XCD reads one 1 MB f-half).
// ---------------------------------------------------------------------------
__global__ __launch_bounds__(256, 2) void k_fused(
    const f16* __restrict__ t1p, const f16* __restrict__ v1,
    const float* __restrict__ bfc, const f16* __restrict__ w2T,
    f16* __restrict__ t2p)
{
    __shared__ __align__(16) char smem[16896];     // hs 8KB | reduce overlay

    const int tid  = threadIdx.x;
    const int lane = tid & 63;
    const int wv   = tid >> 6;                     // 0..3
    const int c    = lane & 15, q = lane >> 4;

    // XCD swizzle (bijective, 1024 = 128*8): XCDs 0-3 -> s=0, 4-7 -> s=1
    const int bx  = blockIdx.x;
    const int s   = (bx & 7) >> 2;
    const int mb  = (bx >> 3) * 4 + (bx & 3);      // 0..511
    const int m0b = mb * 16;
    const int f00 = s * 2048 + wv * 512;

    char* hsb = &smem[wv * 2048];                  // per-wave h scratch [16][128B]

    // A2 fragments: f16 sum of the two t1 partials (proven), 16 rows
    f16x8 a2[4];
#pragma unroll
    for (int kb = 0; kb < 4; ++kb) {
        const size_t off = (size_t)(m0b + c) * RANK + kb * 32 + q * 8;
        f16x8 p0 = ld8(t1p + off);
        f16x8 p1 = ld8(t1p + (size_t)(M_ROWS * RANK) + off);
#pragma unroll
        for (int e = 0; e < 8; ++e)
            a2[kb][e] = (f16)((float)p0[e] + (float)p1[e]);
    }

    f32x4 c3[8] = {};

#pragma unroll 1
    for (int ch = 0; ch < 8; ++ch) {
        const int f0 = f00 + ch * 64;

        // ---- load stage-2 B frags (bv dies at end of stage 2)
        f16x8 bv[4][4];
#pragma unroll
        for (int nt = 0; nt < 4; ++nt)
#pragma unroll
            for (int kb = 0; kb < 4; ++kb)
                bv[nt][kb] = ld8(v1 + (size_t)(f0 + nt * 16 + c) * RANK + kb * 32 + q * 8);
        // bias loads fly under stage 2
        float bb[4];
#pragma unroll
        for (int nt = 0; nt < 4; ++nt)
            bb[nt] = bfc[f0 + nt * 16 + c];

        // ---- stage 2: h-tile = t1 @ v1^T
        f32x4 c2[4] = {};
#pragma unroll
        for (int nt = 0; nt < 4; ++nt)
#pragma unroll
            for (int kb = 0; kb < 4; ++kb)
                c2[nt] = MFMA16(a2[kb], bv[nt][kb], c2[nt]);

        // ---- issue stage-3 B frags now; gelu's VALU hides their latency
        f16x8 bw[2][8];
#pragma unroll
        for (int kb2 = 0; kb2 < 2; ++kb2)
#pragma unroll
            for (int rt = 0; rt < 8; ++rt)
                bw[kb2][rt] = ld8(w2T + (size_t)(rt * 16 + c) * D_FF +
                                  f0 + kb2 * 32 + q * 8);

        // ---- bias + gelu -> per-wave hs, XOR-swizzled rows of 128 B
#pragma unroll
        for (int nt = 0; nt < 4; ++nt)
#pragma unroll
            for (int i2 = 0; i2 < 4; ++i2) {
                int row = q * 4 + i2;
                int col = ((nt * 16 + c) * 2) ^ ((row & 7) << 4);
                *(f16*)(hsb + row * 128 + col) =
                    (f16)gelu_fast(c2[nt][i2] + bb[nt]);
            }
        asm volatile("s_waitcnt lgkmcnt(0)" ::: "memory"); // cross-lane RAW

        // ---- stage 3: c3 += h @ w2T^T
#pragma unroll
        for (int kb2 = 0; kb2 < 2; ++kb2) {
            int row = c;
            int col = (kb2 * 64 + q * 16) ^ ((row & 7) << 4);
            f16x8 a3 = *(const f16x8*)(hsb + row * 128 + col);
#pragma unroll
            for (int rt = 0; rt < 8; ++rt)
                c3[rt] = MFMA16(a3, bw[kb2][rt], c3[rt]);
        }
        asm volatile("s_waitcnt lgkmcnt(0)" ::: "memory"); // WAR on hs
    }

    // ---- epilogue: 4-way tree reduce of c3 over wv, write f16 partial t2p[s]
    float* rbuf = (float*)smem;                    // 2 regions of [16][132] f32

#define ST_C3(w)                                                                \
    { float* rb = rbuf + (w) * 2112;                                            \
      _Pragma("unroll") for (int rt = 0; rt < 8; ++rt)                          \
      _Pragma("unroll") for (int i2 = 0; i2 < 4; ++i2)                          \
          rb[(q * 4 + i2) * 132 + rt * 16 + c] = c3[rt][i2]; }
#define ADD_C3(w)                                                               \
    { float* rb = rbuf + (w) * 2112;                                            \
      _Pragma("unroll") for (int rt = 0; rt < 8; ++rt)                          \
      _Pragma("unroll") for (int i2 = 0; i2 < 4; ++i2)                          \
          c3[rt][i2] += rb[(q * 4 + i2) * 132 + rt * 16 + c]; }

    __syncthreads();                               // all waves done with hs
    if (wv >= 2) ST_C3(wv - 2)
    __syncthreads();
    if (wv < 2) ADD_C3(wv)
    __syncthreads();
    if (wv == 1) ST_C3(0)
    __syncthreads();
    if (wv == 0) {
        ADD_C3(0)
        f16* o = t2p + (size_t)s * (M_ROWS * RANK);
#pragma unroll
        for (int rt = 0; rt < 8; ++rt)
#pragma unroll
            for (int i2 = 0; i2 < 4; ++i2)
                o[(size_t)(m0b + q * 4 + i2) * RANK + rt * 16 + c] =
                    (f16)c3[rt][i2];
    }
#undef ST_C3
#undef ADD_C3
}

// ---------------------------------------------------------------------------
// Stage 4 (proven R0/R1): out = (t2p0+t2p1) @ v2^T + bpj, fp32 out.
// ---------------------------------------------------------------------------
__global__ __launch_bounds__(256, 2) void k_out(
    const f16* __restrict__ t2p, const f16* __restrict__ v2,
    const float* __restrict__ bpj, float* __restrict__ out)
{
    __shared__ __align__(16) f16 v2s[256 * 136];

    const int tid  = threadIdx.x;
    const int lane = tid & 63;
    const int wv   = tid >> 6;
    const int wm   = wv & 1, wn = wv >> 1;
    const int m0b  = blockIdx.x * 32;
    const int n0b  = blockIdx.y * 256;
    const int c    = lane & 15, q = lane >> 4;

#pragma unroll
    for (int i8 = 0; i8 < 16; ++i8) {
        int id = i8 * 256 + tid;
        int nn = id >> 4, k8 = id & 15;
        *(f16x8*)&v2s[nn * 136 + k8 * 8] =
            ld8(v2 + (size_t)(n0b + nn) * RANK + k8 * 8);
    }

    f16x8 a[4];
#pragma unroll
    for (int kb = 0; kb < 4; ++kb) {
        const size_t off = (size_t)(m0b + wm * 16 + c) * RANK + kb * 32 + q * 8;
        f16x8 p0 = ld8(t2p + off);
        f16x8 p1 = ld8(t2p + (size_t)(M_ROWS * RANK) + off);
#pragma unroll
        for (int e = 0; e < 8; ++e)
            a[kb][e] = (f16)((float)p0[e] + (float)p1[e]);
    }
    __syncthreads();

    f32x4 acc[8] = {};
#pragma unroll
    for (int nt = 0; nt < 8; ++nt)
#pragma unroll
        for (int kb = 0; kb < 4; ++kb) {
            f16x8 bf = *(const f16x8*)
                &v2s[(wn * 128 + nt * 16 + c) * 136 + kb * 32 + q * 8];
            acc[nt] = MFMA16(a[kb], bf, acc[nt]);
        }

#pragma unroll
    for (int nt = 0; nt < 8; ++nt) {
        float b = bpj[n0b + wn * 128 + nt * 16 + c];
#pragma unroll
        for (int i2 = 0; i2 < 4; ++i2)
            out[(size_t)(m0b + wm * 16 + q * 4 + i2) * D_MODEL +
                n0b + wn * 128 + nt * 16 + c] = acc[nt][i2] + b;
    }
}

extern "C" void kernel_launch(void* const* d_in, const int* in_sizes, int n_in,
                              void* d_out, int out_size, void* d_ws, size_t ws_size,
                              hipStream_t stream) {
    const float* x    = (const float*)d_in[0];
    const float* cfcU = (const float*)d_in[1];
    const float* cfcS = (const float*)d_in[2];
    const float* cfcV = (const float*)d_in[3];
    const float* cfcB = (const float*)d_in[4];
    const float* pjU  = (const float*)d_in[5];
    const float* pjS  = (const float*)d_in[6];
    const float* pjV  = (const float*)d_in[7];
    const float* pjB  = (const float*)d_in[8];
    float* out = (float*)d_out;

    // ws layout (f16 elements), 10.5 MB (12 MB proven safe):
    f16* wsf = (f16*)d_ws;
    f16* t1p = wsf;                 // [2][8192*128]  4 MB
    f16* t2p = wsf + 2097152;       // [2][8192*128]  4 MB
    f16* w1T = wsf + 4194304;       // [128*1024]
    f16* v1  = w1T + 131072;        // [4096*128]
    f16* w2T = v1  + 524288;        // [128*4096]
    f16* v2  = w2T + 524288;        // [1024*128]

    k_prep <<<dim3(5120), 256, 0, stream>>>(cfcU, cfcS, cfcV, pjU, pjS, pjV,
                                            w1T, v1, w2T, v2);
    k_t1   <<<dim3(M_ROWS / 64, 2), 512, 0, stream>>>(x, w1T, t1p);
    k_fused<<<dim3(1024), 256, 0, stream>>>(t1p, v1, cfcB, w2T, t2p);
    k_out  <<<dim3(M_ROWS / 32, D_MODEL / 256), 256, 0, stream>>>(t2p, v2, pjB, out);
}

// Round 7
// 201.397 us; speedup vs baseline: 1.3129x; 1.1947x over previous
//
#include <hip/hip_runtime.h>
#include <math.h>

#define D_MODEL 1024
#define D_FF    4096
#define RANK    128
#define M_ROWS  8192

typedef _Float16 f16;
typedef _Float16 f16x8 __attribute__((ext_vector_type(8)));
typedef float    f32x4 __attribute__((ext_vector_type(4)));

#define MFMA16(a, b, c) __builtin_amdgcn_mfma_f32_16x16x32_f16((a), (b), (c), 0, 0, 0)

__device__ __forceinline__ f16x8 ld8(const f16* p) { return *(const f16x8*)p; }

__device__ __forceinline__ f16x8 cvt8(float4 a0, float4 a1) {
    f16x8 r = { (f16)a0.x, (f16)a0.y, (f16)a0.z, (f16)a0.w,
                (f16)a1.x, (f16)a1.y, (f16)a1.z, (f16)a1.w };
    return r;
}

// Fast exact-gelu: erf via Abramowitz-Stegun 7.1.26 (proven R2/R4, absmax 9.77e-4).
__device__ __forceinline__ float gelu_fast(float v) {
    float u  = v * 0.70710678118654752440f;
    float au = fabsf(u);
    float t  = __builtin_amdgcn_rcpf(__builtin_fmaf(0.3275911f, au, 1.0f));
    float e  = __expf(-au * au);
    float p  = __builtin_fmaf(1.061405429f, t, -1.453152027f);
    p = __builtin_fmaf(p, t, 1.421413741f);
    p = __builtin_fmaf(p, t, -0.284496736f);
    p = __builtin_fmaf(p, t, 0.254829592f);
    float er = __builtin_fmaf(-p * t, e, 1.0f);
    er = copysignf(er, u);
    return 0.5f * v * (1.0f + er);
}

// ---------------------------------------------------------------------------
// Prep (verbatim-proven).
// ---------------------------------------------------------------------------
__global__ __launch_bounds__(256) void k_prep(
    const float* __restrict__ cfcU, const float* __restrict__ cfcS,
    const float* __restrict__ cfcV, const float* __restrict__ pjU,
    const float* __restrict__ pjS,  const float* __restrict__ pjV,
    f16* __restrict__ w1T, f16* __restrict__ v1,
    f16* __restrict__ w2T, f16* __restrict__ v2)
{
    int i = blockIdx.x * 256 + threadIdx.x;
    if (i < 131072) {
        int r = i >> 10, d = i & 1023;
        w1T[i] = (f16)(cfcU[d * RANK + r] * cfcS[r]);
    } else if (i < 655360) {
        int j = i - 131072;
        v1[j] = (f16)cfcV[j];
    } else if (i < 1179648) {
        int j = i - 655360;
        int r = j >> 12, f = j & 4095;
        w2T[j] = (f16)(pjU[f * RANK + r] * pjS[r]);
    } else if (i < 1310720) {
        int j = i - 1179648;
        v2[j] = (f16)pjV[j];
    }
}

// ---------------------------------------------------------------------------
// Stage 1 (proven R1): t1p[h][m][r] = x[m][K-half h] @ w1T^T.
// ---------------------------------------------------------------------------
__global__ __launch_bounds__(512, 2) void k_t1(
    const float* __restrict__ x, const f16* __restrict__ w1T,
    f16* __restrict__ t1p)
{
    __shared__ __align__(16) f16 w1s[128 * 520];   // 133120 B

    const int tid  = threadIdx.x;
    const int lane = tid & 63;
    const int wv   = tid >> 6;
    const int wm   = wv & 3, wn = wv >> 2;
    const int m0b  = blockIdx.x * 64;
    const int h    = blockIdx.y;
    const int c    = lane & 15, q = lane >> 4;

#define LOADX(dst, kc)                                                          \
    _Pragma("unroll") for (int kb = 0; kb < 4; ++kb) {                          \
        const float* px = &x[(size_t)(m0b + wm * 16 + c) * D_MODEL +            \
                             h * 512 + (kc) * 128 + kb * 32 + q * 8];           \
        dst[kb][0] = *(const float4*)px;                                        \
        dst[kb][1] = *(const float4*)(px + 4); }

#define COMPUTEKC(src, kc)                                                      \
    _Pragma("unroll") for (int kb = 0; kb < 4; ++kb) {                          \
        f16x8 af = cvt8(src[kb][0], src[kb][1]);                                \
        _Pragma("unroll") for (int nt = 0; nt < 4; ++nt) {                      \
            f16x8 bf = *(const f16x8*)                                          \
                &w1s[(wn * 64 + nt * 16 + c) * 520 + (kc) * 128 + kb * 32 + q * 8]; \
            acc[nt] = MFMA16(af, bf, acc[nt]); } }

    float4 xa[4][2], xb[4][2];
    LOADX(xa, 0)

#pragma unroll
    for (int i = 0; i < 16; ++i) {
        int id = i * 512 + tid;
        int rr = id >> 6, k8 = id & 63;
        *(f16x8*)&w1s[rr * 520 + k8 * 8] =
            ld8(w1T + (size_t)rr * D_MODEL + h * 512 + k8 * 8);
    }
    __syncthreads();

    f32x4 acc[4] = {};
    LOADX(xb, 1)
    COMPUTEKC(xa, 0)
    LOADX(xa, 2)
    COMPUTEKC(xb, 1)
    LOADX(xb, 3)
    COMPUTEKC(xa, 2)
    COMPUTEKC(xb, 3)

    f16* o = t1p + (size_t)h * (M_ROWS * RANK);
#pragma unroll
    for (int nt = 0; nt < 4; ++nt)
#pragma unroll
        for (int i2 = 0; i2 < 4; ++i2)
            o[(size_t)(m0b + wm * 16 + q * 4 + i2) * RANK + wn * 64 + nt * 16 + c] =
                (f16)acc[nt][i2];
#undef LOADX
#undef COMPUTEKC
}

// ---------------------------------------------------------------------------
// Fused stages 2+3 v7 = R4 body (BM=32, zero-spill-proven at 128-VGPR cap,
// 0 bank conflicts) at DOUBLE WAVE RESIDENCY. R6 post-mortem: BM=16 doubled
// weight traffic (1 GB) and halved MFMA-per-load — occupancy gain was eaten.
// v7 keeps BM=32 and the 512-block grid (512 MB traffic, same per-wave
// chain), but packs 8 waves per 512-thr block: wave wv owns f-slice
// [s*2048 + wv*256, +256) in 4 chunks of 64 f. 2 blocks/CU x 8 waves =
// 4 waves/SIMD (vs R4's 2) -> naked-L2-latency stall (~70% of cycles,
// R4 PMC) gets twice the TLP cover. LDS: hs 8x4KB=32KB | 8-way-reduce
// overlay 67.6KB (R2-proven logic). Cap at (512,2)=128 VGPR (measured
// R1/R2); identical per-thread state to R4 which fit 128 exactly.
// ---------------------------------------------------------------------------
__global__ __launch_bounds__(512, 2) void k_fused(
    const f16* __restrict__ t1p, const f16* __restrict__ v1,
    const float* __restrict__ bfc, const f16* __restrict__ w2T,
    f16* __restrict__ t2p)
{
    __shared__ __align__(16) char smem[67584];     // hs 32KB | reduce overlay

    const int tid  = threadIdx.x;
    const int lane = tid & 63;
    const int wv   = tid >> 6;                     // 0..7 = f-slice owner
    const int c    = lane & 15, q = lane >> 4;

    // XCD swizzle (bijective, 512 = 64*8): XCDs 0-3 -> s=0, 4-7 -> s=1
    const int bx  = blockIdx.x;
    const int s   = (bx & 7) >> 2;
    const int mb  = (bx >> 3) * 4 + (bx & 3);      // 0..255
    const int m0b = mb * 32;
    const int f00 = s * 2048 + wv * 256;

    char* hsb = &smem[wv * 4096];                  // per-wave h scratch [32][128B]

    // A2 fragments: f16 sum of the two t1 partials (proven)
    f16x8 a2[2][4];
#pragma unroll
    for (int wm2 = 0; wm2 < 2; ++wm2)
#pragma unroll
        for (int kb = 0; kb < 4; ++kb) {
            const size_t off = (size_t)(m0b + wm2 * 16 + c) * RANK + kb * 32 + q * 8;
            f16x8 p0 = ld8(t1p + off);
            f16x8 p1 = ld8(t1p + (size_t)(M_ROWS * RANK) + off);
#pragma unroll
            for (int e = 0; e < 8; ++e)
                a2[wm2][kb][e] = (f16)((float)p0[e] + (float)p1[e]);
        }

    f32x4 c3[2][8] = {};

#pragma unroll 1
    for (int ch = 0; ch < 4; ++ch) {
        const int f0 = f00 + ch * 64;

        // ---- load stage-2 B frags (bv dies at end of stage 2)
        f16x8 bv[4][4];
#pragma unroll
        for (int nt = 0; nt < 4; ++nt)
#pragma unroll
            for (int kb = 0; kb < 4; ++kb)
                bv[nt][kb] = ld8(v1 + (size_t)(f0 + nt * 16 + c) * RANK + kb * 32 + q * 8);
        // bias loads fly under stage 2
        float bb[4];
#pragma unroll
        for (int nt = 0; nt < 4; ++nt)
            bb[nt] = bfc[f0 + nt * 16 + c];

        // ---- stage 2: h-tile = t1 @ v1^T (each bv frag feeds 2 MFMA)
        f32x4 c2[2][4] = {};
#pragma unroll
        for (int nt = 0; nt < 4; ++nt)
#pragma unroll
            for (int kb = 0; kb < 4; ++kb) {
                c2[0][nt] = MFMA16(a2[0][kb], bv[nt][kb], c2[0][nt]);
                c2[1][nt] = MFMA16(a2[1][kb], bv[nt][kb], c2[1][nt]);
            }

        // ---- issue stage-3 B frags now; gelu's VALU hides their latency
        f16x8 bw[2][8];
#pragma unroll
        for (int kb2 = 0; kb2 < 2; ++kb2)
#pragma unroll
            for (int rt = 0; rt < 8; ++rt)
                bw[kb2][rt] = ld8(w2T + (size_t)(rt * 16 + c) * D_FF +
                                  f0 + kb2 * 32 + q * 8);

        // ---- bias + gelu -> per-wave hs, XOR-swizzled rows of 128 B
#pragma unroll
        for (int wm2 = 0; wm2 < 2; ++wm2)
#pragma unroll
            for (int nt = 0; nt < 4; ++nt)
#pragma unroll
                for (int i2 = 0; i2 < 4; ++i2) {
                    int row = wm2 * 16 + q * 4 + i2;
                    int col = ((nt * 16 + c) * 2) ^ ((row & 7) << 4);
                    *(f16*)(hsb + row * 128 + col) =
                        (f16)gelu_fast(c2[wm2][nt][i2] + bb[nt]);
                }
        asm volatile("s_waitcnt lgkmcnt(0)" ::: "memory"); // cross-lane RAW

        // ---- stage 3: c3 += h @ w2T^T
#pragma unroll
        for (int kb2 = 0; kb2 < 2; ++kb2) {
            f16x8 a3[2];
#pragma unroll
            for (int wm2 = 0; wm2 < 2; ++wm2) {
                int row = wm2 * 16 + c;
                int col = (kb2 * 64 + q * 16) ^ ((row & 7) << 4);
                a3[wm2] = *(const f16x8*)(hsb + row * 128 + col);
            }
#pragma unroll
            for (int rt = 0; rt < 8; ++rt) {
                c3[0][rt] = MFMA16(a3[0], bw[kb2][rt], c3[0][rt]);
                c3[1][rt] = MFMA16(a3[1], bw[kb2][rt], c3[1][rt]);
            }
        }
        asm volatile("s_waitcnt lgkmcnt(0)" ::: "memory"); // WAR on hs
    }

    // ---- epilogue: 8-way tree reduce of c3 over wv (R2-proven logic),
    //      write f16 partial t2p[s]
    float* rbuf = (float*)smem;                    // 4 regions of [32][132] f32

#define ST_C3(w)                                                                \
    { float* rb = rbuf + (w) * 4224;                                            \
      _Pragma("unroll") for (int wm2 = 0; wm2 < 2; ++wm2)                       \
      _Pragma("unroll") for (int rt = 0; rt < 8; ++rt)                          \
      _Pragma("unroll") for (int i2 = 0; i2 < 4; ++i2)                          \
          rb[(wm2 * 16 + q * 4 + i2) * 132 + rt * 16 + c] = c3[wm2][rt][i2]; }
#define ADD_C3(w)                                                               \
    { float* rb = rbuf + (w) * 4224;                                            \
      _Pragma("unroll") for (int wm2 = 0; wm2 < 2; ++wm2)                       \
      _Pragma("unroll") for (int rt = 0; rt < 8; ++rt)                          \
      _Pragma("unroll") for (int i2 = 0; i2 < 4; ++i2)                          \
          c3[wm2][rt][i2] += rb[(wm2 * 16 + q * 4 + i2) * 132 + rt * 16 + c]; }

    __syncthreads();                               // all waves done with hs
    if (wv >= 4) ST_C3(wv - 4)
    __syncthreads();
    if (wv < 4) ADD_C3(wv)
    __syncthreads();
    if (wv == 2 || wv == 3) ST_C3(wv - 2)
    __syncthreads();
    if (wv < 2) ADD_C3(wv)
    __syncthreads();
    if (wv == 1) ST_C3(0)
    __syncthreads();
    if (wv == 0) {
        ADD_C3(0)
        f16* o = t2p + (size_t)s * (M_ROWS * RANK);
#pragma unroll
        for (int wm2 = 0; wm2 < 2; ++wm2)
#pragma unroll
            for (int rt = 0; rt < 8; ++rt)
#pragma unroll
                for (int i2 = 0; i2 < 4; ++i2)
                    o[(size_t)(m0b + wm2 * 16 + q * 4 + i2) * RANK + rt * 16 + c] =
                        (f16)c3[wm2][rt][i2];
    }
#undef ST_C3
#undef ADD_C3
}

// ---------------------------------------------------------------------------
// Stage 4 (proven R0/R1): out = (t2p0+t2p1) @ v2^T + bpj, fp32 out.
// ---------------------------------------------------------------------------
__global__ __launch_bounds__(256, 2) void k_out(
    const f16* __restrict__ t2p, const f16* __restrict__ v2,
    const float* __restrict__ bpj, float* __restrict__ out)
{
    __shared__ __align__(16) f16 v2s[256 * 136];

    const int tid  = threadIdx.x;
    const int lane = tid & 63;
    const int wv   = tid >> 6;
    const int wm   = wv & 1, wn = wv >> 1;
    const int m0b  = blockIdx.x * 32;
    const int n0b  = blockIdx.y * 256;
    const int c    = lane & 15, q = lane >> 4;

#pragma unroll
    for (int i8 = 0; i8 < 16; ++i8) {
        int id = i8 * 256 + tid;
        int nn = id >> 4, k8 = id & 15;
        *(f16x8*)&v2s[nn * 136 + k8 * 8] =
            ld8(v2 + (size_t)(n0b + nn) * RANK + k8 * 8);
    }

    f16x8 a[4];
#pragma unroll
    for (int kb = 0; kb < 4; ++kb) {
        const size_t off = (size_t)(m0b + wm * 16 + c) * RANK + kb * 32 + q * 8;
        f16x8 p0 = ld8(t2p + off);
        f16x8 p1 = ld8(t2p + (size_t)(M_ROWS * RANK) + off);
#pragma unroll
        for (int e = 0; e < 8; ++e)
            a[kb][e] = (f16)((float)p0[e] + (float)p1[e]);
    }
    __syncthreads();

    f32x4 acc[8] = {};
#pragma unroll
    for (int nt = 0; nt < 8; ++nt)
#pragma unroll
        for (int kb = 0; kb < 4; ++kb) {
            f16x8 bf = *(const f16x8*)
                &v2s[(wn * 128 + nt * 16 + c) * 136 + kb * 32 + q * 8];
            acc[nt] = MFMA16(a[kb], bf, acc[nt]);
        }

#pragma unroll
    for (int nt = 0; nt < 8; ++nt) {
        float b = bpj[n0b + wn * 128 + nt * 16 + c];
#pragma unroll
        for (int i2 = 0; i2 < 4; ++i2)
            out[(size_t)(m0b + wm * 16 + q * 4 + i2) * D_MODEL +
                n0b + wn * 128 + nt * 16 + c] = acc[nt][i2] + b;
    }
}

extern "C" void kernel_launch(void* const* d_in, const int* in_sizes, int n_in,
                              void* d_out, int out_size, void* d_ws, size_t ws_size,
                              hipStream_t stream) {
    const float* x    = (const float*)d_in[0];
    const float* cfcU = (const float*)d_in[1];
    const float* cfcS = (const float*)d_in[2];
    const float* cfcV = (const float*)d_in[3];
    const float* cfcB = (const float*)d_in[4];
    const float* pjU  = (const float*)d_in[5];
    const float* pjS  = (const float*)d_in[6];
    const float* pjV  = (const float*)d_in[7];
    const float* pjB  = (const float*)d_in[8];
    float* out = (float*)d_out;

    // ws layout (f16 elements), 10.5 MB (12 MB proven safe):
    f16* wsf = (f16*)d_ws;
    f16* t1p = wsf;                 // [2][8192*128]  4 MB
    f16* t2p = wsf + 2097152;       // [2][8192*128]  4 MB
    f16* w1T = wsf + 4194304;       // [128*1024]
    f16* v1  = w1T + 131072;        // [4096*128]
    f16* w2T = v1  + 524288;        // [128*4096]
    f16* v2  = w2T + 524288;        // [1024*128]

    k_prep <<<dim3(5120), 256, 0, stream>>>(cfcU, cfcS, cfcV, pjU, pjS, pjV,
                                            w1T, v1, w2T, v2);
    k_t1   <<<dim3(M_ROWS / 64, 2), 512, 0, stream>>>(x, w1T, t1p);
    k_fused<<<dim3(512), 512, 0, stream>>>(t1p, v1, cfcB, w2T, t2p);
    k_out  <<<dim3(M_ROWS / 32, D_MODEL / 256), 256, 0, stream>>>(t2p, v2, pjB, out);
}

// Round 8
// 167.470 us; speedup vs baseline: 1.5789x; 1.2026x over previous
//
#include <hip/hip_runtime.h>
#include <math.h>

#define D_MODEL 1024
#define D_FF    4096
#define RANK    128
#define M_ROWS  8192

typedef _Float16 f16;
typedef _Float16 f16x8 __attribute__((ext_vector_type(8)));
typedef float    f32x4 __attribute__((ext_vector_type(4)));

#define MFMA16(a, b, c) __builtin_amdgcn_mfma_f32_16x16x32_f16((a), (b), (c), 0, 0, 0)

__device__ __forceinline__ f16x8 ld8(const f16* p) { return *(const f16x8*)p; }

__device__ __forceinline__ f16x8 cvt8(float4 a0, float4 a1) {
    f16x8 r = { (f16)a0.x, (f16)a0.y, (f16)a0.z, (f16)a0.w,
                (f16)a1.x, (f16)a1.y, (f16)a1.z, (f16)a1.w };
    return r;
}

// Fast exact-gelu (proven R2/R4, absmax 9.77e-4).
__device__ __forceinline__ float gelu_fast(float v) {
    float u  = v * 0.70710678118654752440f;
    float au = fabsf(u);
    float t  = __builtin_amdgcn_rcpf(__builtin_fmaf(0.3275911f, au, 1.0f));
    float e  = __expf(-au * au);
    float p  = __builtin_fmaf(1.061405429f, t, -1.453152027f);
    p = __builtin_fmaf(p, t, 1.421413741f);
    p = __builtin_fmaf(p, t, -0.284496736f);
    p = __builtin_fmaf(p, t, 0.254829592f);
    float er = __builtin_fmaf(-p * t, e, 1.0f);
    er = copysignf(er, u);
    return 0.5f * v * (1.0f + er);
}

// async global->LDS, 16 B per lane; LDS dest wave-uniform base + lane*16
#define GLOAD16(gp, lp) __builtin_amdgcn_global_load_lds(                     \
    (const __attribute__((address_space(1))) void*)(gp),                      \
    (__attribute__((address_space(3))) void*)(lp), 16, 0, 0)

// ---------------------------------------------------------------------------
// Prep (verbatim-proven).
// ---------------------------------------------------------------------------
__global__ __launch_bounds__(256) void k_prep(
    const float* __restrict__ cfcU, const float* __restrict__ cfcS,
    const float* __restrict__ cfcV, const float* __restrict__ pjU,
    const float* __restrict__ pjS,  const float* __restrict__ pjV,
    f16* __restrict__ w1T, f16* __restrict__ v1,
    f16* __restrict__ w2T, f16* __restrict__ v2)
{
    int i = blockIdx.x * 256 + threadIdx.x;
    if (i < 131072) {
        int r = i >> 10, d = i & 1023;
        w1T[i] = (f16)(cfcU[d * RANK + r] * cfcS[r]);
    } else if (i < 655360) {
        int j = i - 131072;
        v1[j] = (f16)cfcV[j];
    } else if (i < 1179648) {
        int j = i - 655360;
        int r = j >> 12, f = j & 4095;
        w2T[j] = (f16)(pjU[f * RANK + r] * pjS[r]);
    } else if (i < 1310720) {
        int j = i - 1179648;
        v2[j] = (f16)pjV[j];
    }
}

// ---------------------------------------------------------------------------
// Stage 1 (proven R1): t1p[h][m][r] = x[m][K-half h] @ w1T^T.
// ---------------------------------------------------------------------------
__global__ __launch_bounds__(512, 2) void k_t1(
    const float* __restrict__ x, const f16* __restrict__ w1T,
    f16* __restrict__ t1p)
{
    __shared__ __align__(16) f16 w1s[128 * 520];   // 133120 B

    const int tid  = threadIdx.x;
    const int lane = tid & 63;
    const int wv   = tid >> 6;
    const int wm   = wv & 3, wn = wv >> 2;
    const int m0b  = blockIdx.x * 64;
    const int h    = blockIdx.y;
    const int c    = lane & 15, q = lane >> 4;

#define LOADX(dst, kc)                                                          \
    _Pragma("unroll") for (int kb = 0; kb < 4; ++kb) {                          \
        const float* px = &x[(size_t)(m0b + wm * 16 + c) * D_MODEL +            \
                             h * 512 + (kc) * 128 + kb * 32 + q * 8];           \
        dst[kb][0] = *(const float4*)px;                                        \
        dst[kb][1] = *(const float4*)(px + 4); }

#define COMPUTEKC(src, kc)                                                      \
    _Pragma("unroll") for (int kb = 0; kb < 4; ++kb) {                          \
        f16x8 af = cvt8(src[kb][0], src[kb][1]);                                \
        _Pragma("unroll") for (int nt = 0; nt < 4; ++nt) {                      \
            f16x8 bf = *(const f16x8*)                                          \
                &w1s[(wn * 64 + nt * 16 + c) * 520 + (kc) * 128 + kb * 32 + q * 8]; \
            acc[nt] = MFMA16(af, bf, acc[nt]); } }

    float4 xa[4][2], xb[4][2];
    LOADX(xa, 0)

#pragma unroll
    for (int i = 0; i < 16; ++i) {
        int id = i * 512 + tid;
        int rr = id >> 6, k8 = id & 63;
        *(f16x8*)&w1s[rr * 520 + k8 * 8] =
            ld8(w1T + (size_t)rr * D_MODEL + h * 512 + k8 * 8);
    }
    __syncthreads();

    f32x4 acc[4] = {};
    LOADX(xb, 1)
    COMPUTEKC(xa, 0)
    LOADX(xa, 2)
    COMPUTEKC(xb, 1)
    LOADX(xb, 3)
    COMPUTEKC(xa, 2)
    COMPUTEKC(xb, 3)

    f16* o = t1p + (size_t)h * (M_ROWS * RANK);
#pragma unroll
    for (int nt = 0; nt < 4; ++nt)
#pragma unroll
        for (int i2 = 0; i2 < 4; ++i2)
            o[(size_t)(m0b + wm * 16 + q * 4 + i2) * RANK + wn * 64 + nt * 16 + c] =
                (f16)acc[nt][i2];
#undef LOADX
#undef COMPUTEKC
}

// ---------------------------------------------------------------------------
// Fused stages 2+3 v8: R0's LDS-staged structure (69.5 us proven, best) with
// the T3-minimum async pipeline. R4-R7 proved L2-direct B-frags plateau at
// ~90 us (latency-bound, TLP can't cover). v8 changes vs R0:
//  - staging via global_load_lds width=16 (no VGPR round-trip, ~8 issues/thr)
//  - K_STEP=64 f, DOUBLE-BUFFERED: STAGE(next) issued before compute(cur),
//    ONE barrier/iter; load latency hides under MFMA+gelu.
//  - both-sides XOR swizzle (rule #21): linear LDS dest, global source col
//    pre-swizzled ^((row&7)<<4), ds_reads apply same XOR -> ~0 conflicts
//    (R0 had 4.45M conflict cycles).
//  - gelu_fast; bias loaded before STAGE so waits stay counted.
// Waves: 4 (wm=wv&1 m-half of 16, wf=wv>>1 f-half of 32 per 64-f tile).
// Grid (256 m-tiles, 2 s) = 512 blocks; LDS 72704 B -> 2 blocks/CU.
// ---------------------------------------------------------------------------
#define V1OFF 0          // [2][64 f][256 B]  2*16384
#define W2OFF 32768      // [2][128 r][128 B] 2*16384
#define HSOFF 65536      // [4 waves][16 m][56 f16 = 112 B] 7168
#define HSTR  56

__global__ __launch_bounds__(256, 2) void k_fused(
    const f16* __restrict__ t1p, const f16* __restrict__ v1,
    const float* __restrict__ bfc, const f16* __restrict__ w2T,
    f16* __restrict__ t2p)
{
    __shared__ __align__(16) char smem[72704];

    const int tid  = threadIdx.x;
    const int lane = tid & 63;
    const int wv   = tid >> 6;                     // 0..3
    const int wm   = wv & 1, wf = wv >> 1;
    const int c    = lane & 15, q = lane >> 4;

    // XCD swizzle (bijective, 512 = 64*8): XCDs 0-3 -> s=0, 4-7 -> s=1
    const int bx  = blockIdx.x;
    const int s   = (bx & 7) >> 2;
    const int mb  = (bx >> 3) * 4 + (bx & 3);      // 0..255
    const int m0b = mb * 32;
    const int fw  = wf * 32;                       // wave's f-slice in 64-f tile

    f16* hsw = (f16*)(smem + HSOFF + wv * (16 * HSTR * 2));

    // stage a 64-f tile (itn) into buffer bsel: v1 [64][256B], w2T [128][128B],
    // linear LDS dest + pre-swizzled global source column (rule #21)
#define STAGE(bsel, itn) {                                                      \
    const int ft_ = s * 2048 + (itn) * 64;                                      \
    _Pragma("unroll") for (int i = 0; i < 4; ++i) {                             \
        int rb_  = wv * 16 + i * 4;                                             \
        int row_ = rb_ + (lane >> 4);                                           \
        int col_ = ((lane & 15) * 16) ^ ((row_ & 7) << 4);                      \
        GLOAD16((const char*)v1 + (size_t)(ft_ + row_) * 256 + col_,            \
                smem + V1OFF + (bsel) * 16384 + rb_ * 256);                     \
    }                                                                           \
    _Pragma("unroll") for (int i = 0; i < 4; ++i) {                             \
        int rb_  = wv * 32 + i * 8;                                             \
        int row_ = rb_ + (lane >> 3);                                           \
        int col_ = ((lane & 7) * 16) ^ ((row_ & 7) << 4);                       \
        GLOAD16((const char*)w2T + (size_t)row_ * 8192 + (size_t)ft_ * 2 + col_,\
                smem + W2OFF + (bsel) * 16384 + rb_ * 128);                     \
    }                                                                           \
}

    // A2 fragments: f16 sum of the two t1 partials (proven)
    f16x8 a2[4];
#pragma unroll
    for (int kb = 0; kb < 4; ++kb) {
        const size_t off = (size_t)(m0b + wm * 16 + c) * RANK + kb * 32 + q * 8;
        f16x8 p0 = ld8(t1p + off);
        f16x8 p1 = ld8(t1p + (size_t)(M_ROWS * RANK) + off);
#pragma unroll
        for (int e = 0; e < 8; ++e)
            a2[kb][e] = (f16)((float)p0[e] + (float)p1[e]);
    }

    STAGE(0, 0)
    __syncthreads();                               // buf0 landed (vmcnt drain)

    f32x4 c3[8] = {};

#pragma unroll 1
    for (int it = 0; it < 32; ++it) {
        const int cur = it & 1;
        const int ft  = s * 2048 + it * 64;

        // bias first (waits stay counted: stage loads may remain in flight)
        float bb[2];
        bb[0] = bfc[ft + fw + c];
        bb[1] = bfc[ft + fw + 16 + c];

        if (it < 31) STAGE(cur ^ 1, it + 1)        // prefetch next tile

        // ---- stage 2: h[16m][32f] = t1 @ v1^T (2 nt x 4 kb MFMA)
        f32x4 c2[2] = {};
#pragma unroll
        for (int nt = 0; nt < 2; ++nt)
#pragma unroll
            for (int kb = 0; kb < 4; ++kb) {
                int row = fw + nt * 16 + c;
                f16x8 bv = *(const f16x8*)(smem + V1OFF + cur * 16384 +
                    row * 256 + ((kb * 64 + q * 16) ^ ((row & 7) << 4)));
                c2[nt] = MFMA16(a2[kb], bv, c2[nt]);
            }

        // ---- bias + gelu -> per-wave hs [16][HSTR]
#pragma unroll
        for (int nt = 0; nt < 2; ++nt)
#pragma unroll
            for (int i2 = 0; i2 < 4; ++i2)
                hsw[(q * 4 + i2) * HSTR + nt * 16 + c] =
                    (f16)gelu_fast(c2[nt][i2] + bb[nt]);
        asm volatile("s_waitcnt lgkmcnt(0)" ::: "memory"); // cross-lane RAW

        // ---- stage 3: c3 += h @ w2T^T (K=32, 8 rt MFMA)
        f16x8 a3 = *(const f16x8*)(hsw + c * HSTR + q * 8);
#pragma unroll
        for (int rt = 0; rt < 8; ++rt) {
            int rr = rt * 16 + c;
            f16x8 bw = *(const f16x8*)(smem + W2OFF + cur * 16384 +
                rr * 128 + ((wf * 64 + q * 16) ^ ((c & 7) << 4)));
            c3[rt] = MFMA16(a3, bw, c3[rt]);
        }
        asm volatile("s_waitcnt lgkmcnt(0)" ::: "memory"); // WAR on hs

        __syncthreads();   // next-tile loads landed (vmcnt drain) + hs/tiles safe
    }
#undef STAGE

    // ---- epilogue: 2-wave reduce over wf (R0-proven), write f16 t2p[s]
    float* rbuf = (float*)smem;                    // overlay, 2x[16][132] f32/wm

    if (wf == 1) {
        float* rb = rbuf + wm * 2112;
#pragma unroll
        for (int rt = 0; rt < 8; ++rt)
#pragma unroll
            for (int i2 = 0; i2 < 4; ++i2)
                rb[(q * 4 + i2) * 132 + rt * 16 + c] = c3[rt][i2];
    }
    __syncthreads();
    if (wf == 0) {
        float* rb = rbuf + wm * 2112;
#pragma unroll
        for (int rt = 0; rt < 8; ++rt)
#pragma unroll
            for (int i2 = 0; i2 < 4; ++i2)
                c3[rt][i2] += rb[(q * 4 + i2) * 132 + rt * 16 + c];
        f16* o = t2p + (size_t)s * (M_ROWS * RANK);
#pragma unroll
        for (int rt = 0; rt < 8; ++rt)
#pragma unroll
            for (int i2 = 0; i2 < 4; ++i2)
                o[(size_t)(m0b + wm * 16 + q * 4 + i2) * RANK + rt * 16 + c] =
                    (f16)c3[rt][i2];
    }
}

// ---------------------------------------------------------------------------
// Stage 4 (proven R0/R1): out = (t2p0+t2p1) @ v2^T + bpj, fp32 out.
// ---------------------------------------------------------------------------
__global__ __launch_bounds__(256, 2) void k_out(
    const f16* __restrict__ t2p, const f16* __restrict__ v2,
    const float* __restrict__ bpj, float* __restrict__ out)
{
    __shared__ __align__(16) f16 v2s[256 * 136];

    const int tid  = threadIdx.x;
    const int lane = tid & 63;
    const int wv   = tid >> 6;
    const int wm   = wv & 1, wn = wv >> 1;
    const int m0b  = blockIdx.x * 32;
    const int n0b  = blockIdx.y * 256;
    const int c    = lane & 15, q = lane >> 4;

#pragma unroll
    for (int i8 = 0; i8 < 16; ++i8) {
        int id = i8 * 256 + tid;
        int nn = id >> 4, k8 = id & 15;
        *(f16x8*)&v2s[nn * 136 + k8 * 8] =
            ld8(v2 + (size_t)(n0b + nn) * RANK + k8 * 8);
    }

    f16x8 a[4];
#pragma unroll
    for (int kb = 0; kb < 4; ++kb) {
        const size_t off = (size_t)(m0b + wm * 16 + c) * RANK + kb * 32 + q * 8;
        f16x8 p0 = ld8(t2p + off);
        f16x8 p1 = ld8(t2p + (size_t)(M_ROWS * RANK) + off);
#pragma unroll
        for (int e = 0; e < 8; ++e)
            a[kb][e] = (f16)((float)p0[e] + (float)p1[e]);
    }
    __syncthreads();

    f32x4 acc[8] = {};
#pragma unroll
    for (int nt = 0; nt < 8; ++nt)
#pragma unroll
        for (int kb = 0; kb < 4; ++kb) {
            f16x8 bf = *(const f16x8*)
                &v2s[(wn * 128 + nt * 16 + c) * 136 + kb * 32 + q * 8];
            acc[nt] = MFMA16(a[kb], bf, acc[nt]);
        }

#pragma unroll
    for (int nt = 0; nt < 8; ++nt) {
        float b = bpj[n0b + wn * 128 + nt * 16 + c];
#pragma unroll
        for (int i2 = 0; i2 < 4; ++i2)
            out[(size_t)(m0b + wm * 16 + q * 4 + i2) * D_MODEL +
                n0b + wn * 128 + nt * 16 + c] = acc[nt][i2] + b;
    }
}

extern "C" void kernel_launch(void* const* d_in, const int* in_sizes, int n_in,
                              void* d_out, int out_size, void* d_ws, size_t ws_size,
                              hipStream_t stream) {
    const float* x    = (const float*)d_in[0];
    const float* cfcU = (const float*)d_in[1];
    const float* cfcS = (const float*)d_in[2];
    const float* cfcV = (const float*)d_in[3];
    const float* cfcB = (const float*)d_in[4];
    const float* pjU  = (const float*)d_in[5];
    const float* pjS  = (const float*)d_in[6];
    const float* pjV  = (const float*)d_in[7];
    const float* pjB  = (const float*)d_in[8];
    float* out = (float*)d_out;

    // ws layout (f16 elements), 10.5 MB (12 MB proven safe):
    f16* wsf = (f16*)d_ws;
    f16* t1p = wsf;                 // [2][8192*128]  4 MB
    f16* t2p = wsf + 2097152;       // [2][8192*128]  4 MB
    f16* w1T = wsf + 4194304;       // [128*1024]
    f16* v1  = w1T + 131072;        // [4096*128]
    f16* w2T = v1  + 524288;        // [128*4096]
    f16* v2  = w2T + 524288;        // [1024*128]

    k_prep <<<dim3(5120), 256, 0, stream>>>(cfcU, cfcS, cfcV, pjU, pjS, pjV,
                                            w1T, v1, w2T, v2);
    k_t1   <<<dim3(M_ROWS / 64, 2), 512, 0, stream>>>(x, w1T, t1p);
    k_fused<<<dim3(512), 256, 0, stream>>>(t1p, v1, cfcB, w2T, t2p);
    k_out  <<<dim3(M_ROWS / 32, D_MODEL / 256), 256, 0, stream>>>(t2p, v2, pjB, out);
}

// Round 9
// 167.052 us; speedup vs baseline: 1.5828x; 1.0025x over previous
//
#include <hip/hip_runtime.h>
#include <math.h>

#define D_MODEL 1024
#define D_FF    4096
#define RANK    128
#define M_ROWS  8192

typedef _Float16 f16;
typedef _Float16 f16x8 __attribute__((ext_vector_type(8)));
typedef _Float16 f16x4 __attribute__((ext_vector_type(4)));
typedef float    f32x4 __attribute__((ext_vector_type(4)));

#define MFMA16(a, b, c) __builtin_amdgcn_mfma_f32_16x16x32_f16((a), (b), (c), 0, 0, 0)

__device__ __forceinline__ f16x8 ld8(const f16* p) { return *(const f16x8*)p; }

__device__ __forceinline__ f16x8 cvt8(float4 a0, float4 a1) {
    f16x8 r = { (f16)a0.x, (f16)a0.y, (f16)a0.z, (f16)a0.w,
                (f16)a1.x, (f16)a1.y, (f16)a1.z, (f16)a1.w };
    return r;
}

// Fast exact-gelu (proven R2/R4/R8, absmax 9.77e-4).
__device__ __forceinline__ float gelu_fast(float v) {
    float u  = v * 0.70710678118654752440f;
    float au = fabsf(u);
    float t  = __builtin_amdgcn_rcpf(__builtin_fmaf(0.3275911f, au, 1.0f));
    float e  = __expf(-au * au);
    float p  = __builtin_fmaf(1.061405429f, t, -1.453152027f);
    p = __builtin_fmaf(p, t, 1.421413741f);
    p = __builtin_fmaf(p, t, -0.284496736f);
    p = __builtin_fmaf(p, t, 0.254829592f);
    float er = __builtin_fmaf(-p * t, e, 1.0f);
    er = copysignf(er, u);
    return 0.5f * v * (1.0f + er);
}

// async global->LDS, 16 B per lane; LDS dest wave-uniform base + lane*16
#define GLOAD16(gp, lp) __builtin_amdgcn_global_load_lds(                     \
    (const __attribute__((address_space(1))) void*)(gp),                      \
    (__attribute__((address_space(3))) void*)(lp), 16, 0, 0)

// ---------------------------------------------------------------------------
// Prep v2: R8 post-mortem — old k_prep did stride-512B scalar reads (64
// lanes x 64 lines/wave) for the U transposes and scalar V copies.
// v2: blocks 0..319: V copies vectorized (2x float4 -> f16x8, 8 elems/thr).
//     blocks 320..447: cfcU 32x32 LDS-tiled transpose+scale -> w1T.
//     blocks 448..959: pjU  32x32 LDS-tiled transpose+scale -> w2T.
// Both sides coalesced; +1-pad tile kills bank conflicts.
// ---------------------------------------------------------------------------
__global__ __launch_bounds__(256) void k_prep(
    const float* __restrict__ cfcU, const float* __restrict__ cfcS,
    const float* __restrict__ cfcV, const float* __restrict__ pjU,
    const float* __restrict__ pjS,  const float* __restrict__ pjV,
    f16* __restrict__ w1T, f16* __restrict__ v1,
    f16* __restrict__ w2T, f16* __restrict__ v2)
{
    __shared__ float tile[32][33];
    const int b = blockIdx.x, t = threadIdx.x;

    if (b < 320) {                       // V copies: 320*256*8 = 655360 elems
        int j = (b * 256 + t) * 8;
        const float* src; f16* dst;
        if (j < 524288) { src = cfcV + j;            dst = v1 + j; }
        else            { src = pjV + (j - 524288);  dst = v2 + (j - 524288); }
        float4 a0 = *(const float4*)src, a1 = *(const float4*)(src + 4);
        *(f16x8*)dst = cvt8(a0, a1);
        return;
    }

    // tiled transpose+scale: dst[r][d] = src[d][r] * S[r]
    const float* src; const float* S; f16* dst; int R, tb;
    if (b < 448) { src = cfcU; S = cfcS; dst = w1T; R = 1024; tb = b - 320; }
    else         { src = pjU;  S = pjS;  dst = w2T; R = 4096; tb = b - 448; }
    const int td = tb >> 2, tr = tb & 3;     // 32-row d-tile, 32-col r-tile

    const int r0 = t >> 3, c0 = (t & 7) * 4;
    float4 v  = *(const float4*)(src + (size_t)(td * 32 + r0) * 128 + tr * 32 + c0);
    float4 sv = *(const float4*)(S + tr * 32 + c0);
    tile[r0][c0 + 0] = v.x * sv.x;
    tile[r0][c0 + 1] = v.y * sv.y;
    tile[r0][c0 + 2] = v.z * sv.z;
    tile[r0][c0 + 3] = v.w * sv.w;
    __syncthreads();

    const int j = t >> 3, i4 = (t & 7) * 4;
    f16x4 o = { (f16)tile[i4 + 0][j], (f16)tile[i4 + 1][j],
                (f16)tile[i4 + 2][j], (f16)tile[i4 + 3][j] };
    *(f16x4*)&dst[(size_t)(tr * 32 + j) * R + td * 32 + i4] = o;
}

// ---------------------------------------------------------------------------
// Stage 1 v3: t1p[h][m][r] = x[m][K-half h] @ w1T^T. R8 post-mortem: old
// k_t1 was 256 blocks = 1 block/CU with 133 KB LDS and serial VGPR staging.
// v3: 256-thr blocks, BM=32, grid (256 m-tiles, 2 h) = 512 = 2 blocks/CU.
// w1T K-half staged in TWO 64 KB chunks via global_load_lds (linear LDS rows
// of 512 B + pre-swizzled source col ^((row&7)<<4), k_fused-proven pattern);
// x direct reg loads pipelined between chunks. Accumulation order (kc 0..3)
// identical to R1-proven version -> bit-identical t1p.
// ---------------------------------------------------------------------------
__global__ __launch_bounds__(256, 2) void k_t1(
    const float* __restrict__ x, const f16* __restrict__ w1T,
    f16* __restrict__ t1p)
{
    __shared__ __align__(16) char w1s[65536];      // [128 r][512 B] linear

    const int tid  = threadIdx.x;
    const int lane = tid & 63;
    const int wv   = tid >> 6;
    const int wm   = wv & 1, wn = wv >> 1;
    const int m0b  = blockIdx.x * 32;
    const int h    = blockIdx.y;
    const int c    = lane & 15, q = lane >> 4;

    // stage chunk kk (256 k) : wave wv covers rows wv*32..+31, 16 issues
#define STAGEW(kk)                                                              \
    _Pragma("unroll") for (int i = 0; i < 16; ++i) {                            \
        int r0_  = wv * 32 + i * 2;                                             \
        int row_ = r0_ + (lane >> 5);                                           \
        int col_ = ((lane & 31) * 16) ^ ((row_ & 7) << 4);                      \
        GLOAD16((const char*)w1T + (size_t)row_ * 2048 + h * 1024 +             \
                (kk) * 512 + col_,                                              \
                w1s + r0_ * 512);                                               \
    }

#define LOADX(dst, kc)                                                          \
    _Pragma("unroll") for (int kb = 0; kb < 4; ++kb) {                          \
        const float* px = &x[(size_t)(m0b + wm * 16 + c) * D_MODEL +            \
                             h * 512 + (kc) * 128 + kb * 32 + q * 8];           \
        dst[kb][0] = *(const float4*)px;                                        \
        dst[kb][1] = *(const float4*)(px + 4); }

    // compute one 128-k sub-chunk sc (0/1) of the staged 256-k tile
#define COMPUTEKC(src, sc)                                                      \
    _Pragma("unroll") for (int kb = 0; kb < 4; ++kb) {                          \
        f16x8 af = cvt8(src[kb][0], src[kb][1]);                                \
        _Pragma("unroll") for (int nt = 0; nt < 4; ++nt) {                      \
            int row_ = wn * 64 + nt * 16 + c;                                   \
            f16x8 bf = *(const f16x8*)(w1s + row_ * 512 +                       \
                (((sc) * 256 + kb * 64 + q * 16) ^ ((row_ & 7) << 4)));         \
            acc[nt] = MFMA16(af, bf, acc[nt]); } }

    float4 xa[4][2], xb[4][2];
    LOADX(xa, 0)
    STAGEW(0)
    __syncthreads();                               // chunk0 landed

    f32x4 acc[4] = {};
    LOADX(xb, 1)
    COMPUTEKC(xa, 0)
    COMPUTEKC(xb, 1)
    __syncthreads();                               // chunk0 reads done
    STAGEW(1)
    LOADX(xa, 2)
    __syncthreads();                               // chunk1 landed
    LOADX(xb, 3)
    COMPUTEKC(xa, 0)
    COMPUTEKC(xb, 1)

    f16* o = t1p + (size_t)h * (M_ROWS * RANK);
#pragma unroll
    for (int nt = 0; nt < 4; ++nt)
#pragma unroll
        for (int i2 = 0; i2 < 4; ++i2)
            o[(size_t)(m0b + wm * 16 + q * 4 + i2) * RANK + wn * 64 + nt * 16 + c] =
                (f16)acc[nt][i2];
#undef STAGEW
#undef LOADX
#undef COMPUTEKC
}

// ---------------------------------------------------------------------------
// Fused stages 2+3 v8 (UNCHANGED from R8: 51.5 us proven).
// ---------------------------------------------------------------------------
#define V1OFF 0          // [2][64 f][256 B]  2*16384
#define W2OFF 32768      // [2][128 r][128 B] 2*16384
#define HSOFF 65536      // [4 waves][16 m][56 f16 = 112 B] 7168
#define HSTR  56

__global__ __launch_bounds__(256, 2) void k_fused(
    const f16* __restrict__ t1p, const f16* __restrict__ v1,
    const float* __restrict__ bfc, const f16* __restrict__ w2T,
    f16* __restrict__ t2p)
{
    __shared__ __align__(16) char smem[72704];

    const int tid  = threadIdx.x;
    const int lane = tid & 63;
    const int wv   = tid >> 6;                     // 0..3
    const int wm   = wv & 1, wf = wv >> 1;
    const int c    = lane & 15, q = lane >> 4;

    // XCD swizzle (bijective, 512 = 64*8): XCDs 0-3 -> s=0, 4-7 -> s=1
    const int bx  = blockIdx.x;
    const int s   = (bx & 7) >> 2;
    const int mb  = (bx >> 3) * 4 + (bx & 3);      // 0..255
    const int m0b = mb * 32;
    const int fw  = wf * 32;                       // wave's f-slice in 64-f tile

    f16* hsw = (f16*)(smem + HSOFF + wv * (16 * HSTR * 2));

#define STAGE(bsel, itn) {                                                      \
    const int ft_ = s * 2048 + (itn) * 64;                                      \
    _Pragma("unroll") for (int i = 0; i < 4; ++i) {                             \
        int rb_  = wv * 16 + i * 4;                                             \
        int row_ = rb_ + (lane >> 4);                                           \
        int col_ = ((lane & 15) * 16) ^ ((row_ & 7) << 4);                      \
        GLOAD16((const char*)v1 + (size_t)(ft_ + row_) * 256 + col_,            \
                smem + V1OFF + (bsel) * 16384 + rb_ * 256);                     \
    }                                                                           \
    _Pragma("unroll") for (int i = 0; i < 4; ++i) {                             \
        int rb_  = wv * 32 + i * 8;                                             \
        int row_ = rb_ + (lane >> 3);                                           \
        int col_ = ((lane & 7) * 16) ^ ((row_ & 7) << 4);                       \
        GLOAD16((const char*)w2T + (size_t)row_ * 8192 + (size_t)ft_ * 2 + col_,\
                smem + W2OFF + (bsel) * 16384 + rb_ * 128);                     \
    }                                                                           \
}

    // A2 fragments: f16 sum of the two t1 partials (proven)
    f16x8 a2[4];
#pragma unroll
    for (int kb = 0; kb < 4; ++kb) {
        const size_t off = (size_t)(m0b + wm * 16 + c) * RANK + kb * 32 + q * 8;
        f16x8 p0 = ld8(t1p + off);
        f16x8 p1 = ld8(t1p + (size_t)(M_ROWS * RANK) + off);
#pragma unroll
        for (int e = 0; e < 8; ++e)
            a2[kb][e] = (f16)((float)p0[e] + (float)p1[e]);
    }

    STAGE(0, 0)
    __syncthreads();                               // buf0 landed (vmcnt drain)

    f32x4 c3[8] = {};

#pragma unroll 1
    for (int it = 0; it < 32; ++it) {
        const int cur = it & 1;
        const int ft  = s * 2048 + it * 64;

        float bb[2];
        bb[0] = bfc[ft + fw + c];
        bb[1] = bfc[ft + fw + 16 + c];

        if (it < 31) STAGE(cur ^ 1, it + 1)        // prefetch next tile

        // ---- stage 2: h[16m][32f] = t1 @ v1^T (2 nt x 4 kb MFMA)
        f32x4 c2[2] = {};
#pragma unroll
        for (int nt = 0; nt < 2; ++nt)
#pragma unroll
            for (int kb = 0; kb < 4; ++kb) {
                int row = fw + nt * 16 + c;
                f16x8 bv = *(const f16x8*)(smem + V1OFF + cur * 16384 +
                    row * 256 + ((kb * 64 + q * 16) ^ ((row & 7) << 4)));
                c2[nt] = MFMA16(a2[kb], bv, c2[nt]);
            }

        // ---- bias + gelu -> per-wave hs [16][HSTR]
#pragma unroll
        for (int nt = 0; nt < 2; ++nt)
#pragma unroll
            for (int i2 = 0; i2 < 4; ++i2)
                hsw[(q * 4 + i2) * HSTR + nt * 16 + c] =
                    (f16)gelu_fast(c2[nt][i2] + bb[nt]);
        asm volatile("s_waitcnt lgkmcnt(0)" ::: "memory"); // cross-lane RAW

        // ---- stage 3: c3 += h @ w2T^T (K=32, 8 rt MFMA)
        f16x8 a3 = *(const f16x8*)(hsw + c * HSTR + q * 8);
#pragma unroll
        for (int rt = 0; rt < 8; ++rt) {
            int rr = rt * 16 + c;
            f16x8 bw = *(const f16x8*)(smem + W2OFF + cur * 16384 +
                rr * 128 + ((wf * 64 + q * 16) ^ ((c & 7) << 4)));
            c3[rt] = MFMA16(a3, bw, c3[rt]);
        }
        asm volatile("s_waitcnt lgkmcnt(0)" ::: "memory"); // WAR on hs

        __syncthreads();   // next-tile loads landed + hs/tiles safe
    }
#undef STAGE

    // ---- epilogue: 2-wave reduce over wf (proven), write f16 t2p[s]
    float* rbuf = (float*)smem;

    if (wf == 1) {
        float* rb = rbuf + wm * 2112;
#pragma unroll
        for (int rt = 0; rt < 8; ++rt)
#pragma unroll
            for (int i2 = 0; i2 < 4; ++i2)
                rb[(q * 4 + i2) * 132 + rt * 16 + c] = c3[rt][i2];
    }
    __syncthreads();
    if (wf == 0) {
        float* rb = rbuf + wm * 2112;
#pragma unroll
        for (int rt = 0; rt < 8; ++rt)
#pragma unroll
            for (int i2 = 0; i2 < 4; ++i2)
                c3[rt][i2] += rb[(q * 4 + i2) * 132 + rt * 16 + c];
        f16* o = t2p + (size_t)s * (M_ROWS * RANK);
#pragma unroll
        for (int rt = 0; rt < 8; ++rt)
#pragma unroll
            for (int i2 = 0; i2 < 4; ++i2)
                o[(size_t)(m0b + wm * 16 + q * 4 + i2) * RANK + rt * 16 + c] =
                    (f16)c3[rt][i2];
    }
}

// ---------------------------------------------------------------------------
// Stage 4 v2: out = (t2p0+t2p1) @ v2^T + bpj. R8 post-mortem: BM=32 staged
// v2 redundantly (64 MB L2) with 2 blocks/CU. v2: BM=64, 512 thr (8 waves:
// wm=wv&3 m-quarter, wn=wv>>2 n-half of 128), grid (128 m, 4 n) = 512
// blocks = 2/CU; v2 staging halved (32 MB), 2x waves per staging event.
// ---------------------------------------------------------------------------
__global__ __launch_bounds__(512, 2) void k_out(
    const f16* __restrict__ t2p, const f16* __restrict__ v2,
    const float* __restrict__ bpj, float* __restrict__ out)
{
    __shared__ __align__(16) f16 v2s[256 * 136];

    const int tid  = threadIdx.x;
    const int lane = tid & 63;
    const int wv   = tid >> 6;
    const int wm   = wv & 3, wn = wv >> 2;
    const int m0b  = blockIdx.x * 64;
    const int n0b  = blockIdx.y * 256;
    const int c    = lane & 15, q = lane >> 4;

#pragma unroll
    for (int i8 = 0; i8 < 8; ++i8) {
        int id = i8 * 512 + tid;
        int nn = id >> 4, k8 = id & 15;
        *(f16x8*)&v2s[nn * 136 + k8 * 8] =
            ld8(v2 + (size_t)(n0b + nn) * RANK + k8 * 8);
    }

    f16x8 a[4];
#pragma unroll
    for (int kb = 0; kb < 4; ++kb) {
        const size_t off = (size_t)(m0b + wm * 16 + c) * RANK + kb * 32 + q * 8;
        f16x8 p0 = ld8(t2p + off);
        f16x8 p1 = ld8(t2p + (size_t)(M_ROWS * RANK) + off);
#pragma unroll
        for (int e = 0; e < 8; ++e)
            a[kb][e] = (f16)((float)p0[e] + (float)p1[e]);
    }
    __syncthreads();

    f32x4 acc[8] = {};
#pragma unroll
    for (int nt = 0; nt < 8; ++nt)
#pragma unroll
        for (int kb = 0; kb < 4; ++kb) {
            f16x8 bf = *(const f16x8*)
                &v2s[(wn * 128 + nt * 16 + c) * 136 + kb * 32 + q * 8];
            acc[nt] = MFMA16(a[kb], bf, acc[nt]);
        }

#pragma unroll
    for (int nt = 0; nt < 8; ++nt) {
        float b = bpj[n0b + wn * 128 + nt * 16 + c];
#pragma unroll
        for (int i2 = 0; i2 < 4; ++i2)
            out[(size_t)(m0b + wm * 16 + q * 4 + i2) * D_MODEL +
                n0b + wn * 128 + nt * 16 + c] = acc[nt][i2] + b;
    }
}

extern "C" void kernel_launch(void* const* d_in, const int* in_sizes, int n_in,
                              void* d_out, int out_size, void* d_ws, size_t ws_size,
                              hipStream_t stream) {
    const float* x    = (const float*)d_in[0];
    const float* cfcU = (const float*)d_in[1];
    const float* cfcS = (const float*)d_in[2];
    const float* cfcV = (const float*)d_in[3];
    const float* cfcB = (const float*)d_in[4];
    const float* pjU  = (const float*)d_in[5];
    const float* pjS  = (const float*)d_in[6];
    const float* pjV  = (const float*)d_in[7];
    const float* pjB  = (const float*)d_in[8];
    float* out = (float*)d_out;

    // ws layout (f16 elements), 10.5 MB (12 MB proven safe):
    f16* wsf = (f16*)d_ws;
    f16* t1p = wsf;                 // [2][8192*128]  4 MB
    f16* t2p = wsf + 2097152;       // [2][8192*128]  4 MB
    f16* w1T = wsf + 4194304;       // [128*1024]
    f16* v1  = w1T + 131072;        // [4096*128]
    f16* w2T = v1  + 524288;        // [128*4096]
    f16* v2  = w2T + 524288;        // [1024*128]

    k_prep <<<dim3(960), 256, 0, stream>>>(cfcU, cfcS, cfcV, pjU, pjS, pjV,
                                           w1T, v1, w2T, v2);
    k_t1   <<<dim3(M_ROWS / 32, 2), 256, 0, stream>>>(x, w1T, t1p);
    k_fused<<<dim3(512), 256, 0, stream>>>(t1p, v1, cfcB, w2T, t2p);
    k_out  <<<dim3(M_ROWS / 64, D_MODEL / 256), 512, 0, stream>>>(t2p, v2, pjB, out);
}